// Round 3
// baseline (7635.342 us; speedup 1.0000x reference)
//
#include <hip/hip_runtime.h>
#include <stdint.h>

typedef float v4f __attribute__((ext_vector_type(4)));
typedef float v2f __attribute__((ext_vector_type(2)));

#define ROT(x, r) __builtin_rotateleft32((uint32_t)(x), (r))

// Threefry-2x32, 20 rounds
#define TF_G1(x0, x1) \
  x0 += x1; x1 = ROT(x1, 13); x1 ^= x0; \
  x0 += x1; x1 = ROT(x1, 15); x1 ^= x0; \
  x0 += x1; x1 = ROT(x1, 26); x1 ^= x0; \
  x0 += x1; x1 = ROT(x1, 6);  x1 ^= x0;

#define TF_G2(x0, x1) \
  x0 += x1; x1 = ROT(x1, 17); x1 ^= x0; \
  x0 += x1; x1 = ROT(x1, 29); x1 ^= x0; \
  x0 += x1; x1 = ROT(x1, 16); x1 ^= x0; \
  x0 += x1; x1 = ROT(x1, 24); x1 ^= x0;

__device__ __forceinline__ void threefry_full(uint32_t k0, uint32_t k1,
                                              uint32_t c0, uint32_t c1,
                                              uint32_t& o0, uint32_t& o1) {
  uint32_t ks2 = k0 ^ k1 ^ 0x1BD11BDAu;
  uint32_t x0 = c0 + k0, x1 = c1 + k1;
  TF_G1(x0, x1); x0 += k1;  x1 += ks2 + 1u;
  TF_G2(x0, x1); x0 += ks2; x1 += k0 + 2u;
  TF_G1(x0, x1); x0 += k0;  x1 += k1 + 3u;
  TF_G2(x0, x1); x0 += k1;  x1 += ks2 + 4u;
  TF_G1(x0, x1); x0 += ks2; x1 += k0 + 5u;
  o0 = x0; o1 = x1;
}

// partitionable-mode draw: counts=(0,cnt), bits = out0 ^ out1
__device__ __forceinline__ uint32_t tf_bits(uint32_t k0, uint32_t k1, uint32_t ks2,
                                            uint32_t cnt) {
  uint32_t x0 = k0;        // c0=0
  uint32_t x1 = cnt + k1;
  TF_G1(x0, x1); x0 += k1;  x1 += ks2 + 1u;
  TF_G2(x0, x1); x0 += ks2; x1 += k0 + 2u;
  TF_G1(x0, x1); x0 += k0;  x1 += k1 + 3u;
  TF_G2(x0, x1); x0 += k1;  x1 += ks2 + 4u;
  TF_G1(x0, x1); x0 += ks2; x1 += k0 + 5u;
  return x0 ^ x1;
}

// 16384 rows, 784 features, 10 outputs, 100 timesteps
// block: 256 threads = 8 rows x 32 lanes; grid 2048
__global__ __launch_bounds__(256, 4)
void snn_lif_kernel(const float* __restrict__ x, const float* __restrict__ W,
                    float* __restrict__ out) {
  // Wp[jj][q][jl][4]: q-th float4 of W[:, j=jl+32*jj]  (o = 4q+c; pads = 0)
  __shared__ __align__(16) float Wp[25 * 3 * 32 * 4];
  __shared__ uint32_t keys[100][2];

  const int tid = threadIdx.x;

  for (int s = tid; s < 25 * 3 * 32 * 4; s += 256) {
    int c = s & 3;
    int jl = (s >> 2) & 31;
    int rest = s >> 7;          // 0..74
    int q = rest % 3;
    int jj = rest / 3;
    int o = q * 4 + c;
    int j = jl + 32 * jj;
    float w = 0.0f;
    if (o < 10 && j < 784) w = W[o * 784 + j];
    Wp[s] = w;
  }
  if (tid < 100) {
    threefry_full(0u, 42u, 0u, (uint32_t)tid, keys[tid][0], keys[tid][1]);
  }
  __syncthreads();

  const int row = blockIdx.x * 8 + (tid >> 5);
  const int hl = tid & 31;
  const uint32_t cntbase = (uint32_t)row * 784u + (uint32_t)hl;

  // ---- prologue: per-lane spike thresholds, hoisted out of the t loop ----
  // xi9[jj] = floor(x * 2^23) << 9 ; compare  bits < xi9  ==  (bits>>9)*2^-23 < x
  // (exact: x from jax.random.uniform is k*2^-23, k < 2^23, so no overflow)
  uint32_t xi9[25];
#pragma unroll
  for (int jj = 0; jj < 25; ++jj) {
    uint32_t j = (uint32_t)(jj * 32) + (uint32_t)hl;
    uint32_t xin = cntbase + (uint32_t)(jj * 32);
    if (xin > 12845055u) xin = 12845055u;       // clamp OOB pad reads
    float xv = x[xin];
    uint32_t k = (uint32_t)(xv * 8388608.0f);
    xi9[jj] = (j < 784u) ? (k << 9) : 0u;       // pad lanes never spike -> s=0
  }

  float v[10], acc[10];
#pragma unroll
  for (int o = 0; o < 10; ++o) { v[o] = 0.0f; acc[o] = 0.0f; }

  const v4f* wq = (const v4f*)&Wp[(size_t)hl * 4];   // + jj*3*32 v4f, imm offsets

  for (int t = 0; t < 100; ++t) {
    uint32_t k0 = __builtin_amdgcn_readfirstlane(keys[t][0]);
    uint32_t k1 = __builtin_amdgcn_readfirstlane(keys[t][1]);
    uint32_t ks2 = k0 ^ k1 ^ 0x1BD11BDAu;

    v2f I01 = {0.0f, 0.0f}, I23 = {0.0f, 0.0f}, I45 = {0.0f, 0.0f},
        I67 = {0.0f, 0.0f}, I89 = {0.0f, 0.0f};

#pragma unroll
    for (int jj = 0; jj < 25; ++jj) {
      const uint32_t bits = tf_bits(k0, k1, ks2, cntbase + (uint32_t)(jj * 32));
      const float s = (bits < xi9[jj]) ? 1.0f : 0.0f;   // bit-exact u<x
      const v2f s2 = {s, s};
      // same Wp layout/order as round 1: wa=wq[0], wb=wq[32], wc=wq[64]
      const v4f wa = wq[jj * 96];
      const v4f wb = wq[jj * 96 + 32];
      const v4f wc = wq[jj * 96 + 64];
      // s in {0,1} -> s*w exact; packed fma == scalar fma value-identically
      I01 += s2 * wa.lo;
      I23 += s2 * wa.hi;
      I45 += s2 * wb.lo;
      I67 += s2 * wb.hi;
      I89 += s2 * wc.lo;
    }

    // butterfly reduce across the row's 32 lanes (same order as round 1)
    v2f Ip[5] = {I01, I23, I45, I67, I89};
#pragma unroll
    for (int p = 0; p < 5; ++p) {
      v2f r = Ip[p];
#pragma unroll
      for (int m = 1; m < 32; m <<= 1) {
        v2f q;
        q.x = __shfl_xor(r.x, m, 32);
        q.y = __shfl_xor(r.y, m, 32);
        r += q;
      }
      Ip[p] = r;
    }
    float I[10] = {Ip[0].x, Ip[0].y, Ip[1].x, Ip[1].y, Ip[2].x,
                   Ip[2].y, Ip[3].x, Ip[3].y, Ip[4].x, Ip[4].y};

    // LIF update (replicated across the 32 lanes of the row)
#pragma unroll
    for (int o = 0; o < 10; ++o) {
      float vv = v[o] + (I[o] - v[o]) * 0.5f;   // v += (I - v)/tau, tau=2 (exact)
      float s = (vv >= 1.0f) ? 1.0f : 0.0f;
      acc[o] += s;
      v[o] = (1.0f - s) * vv;                   // hard reset (exact: 0 or vv)
    }
  }

  if (hl == 0) {
#pragma unroll
    for (int o = 0; o < 10; ++o)
      out[(size_t)row * 10 + o] = acc[o] / 100.0f;
  }
}

extern "C" void kernel_launch(void* const* d_in, const int* in_sizes, int n_in,
                              void* d_out, int out_size, void* d_ws, size_t ws_size,
                              hipStream_t stream) {
  const float* x = (const float*)d_in[0];   // [16384,1,28,28] fp32
  const float* W = (const float*)d_in[1];   // [10,784] fp32
  float* out = (float*)d_out;               // [16384,10] fp32
  hipLaunchKernelGGL(snn_lif_kernel, dim3(2048), dim3(256), 0, stream, x, W, out);
}

// Round 4
// 3629.429 us; speedup vs baseline: 2.1037x; 2.1037x over previous
//
#include <hip/hip_runtime.h>
#include <stdint.h>

typedef float v4f __attribute__((ext_vector_type(4)));
typedef float v2f __attribute__((ext_vector_type(2)));

#define ROT(x, r) __builtin_rotateleft32((uint32_t)(x), (r))

// Threefry-2x32, 20 rounds
#define TF_G1(x0, x1) \
  x0 += x1; x1 = ROT(x1, 13); x1 ^= x0; \
  x0 += x1; x1 = ROT(x1, 15); x1 ^= x0; \
  x0 += x1; x1 = ROT(x1, 26); x1 ^= x0; \
  x0 += x1; x1 = ROT(x1, 6);  x1 ^= x0;

#define TF_G2(x0, x1) \
  x0 += x1; x1 = ROT(x1, 17); x1 ^= x0; \
  x0 += x1; x1 = ROT(x1, 29); x1 ^= x0; \
  x0 += x1; x1 = ROT(x1, 16); x1 ^= x0; \
  x0 += x1; x1 = ROT(x1, 24); x1 ^= x0;

__device__ __forceinline__ void threefry_full(uint32_t k0, uint32_t k1,
                                              uint32_t c0, uint32_t c1,
                                              uint32_t& o0, uint32_t& o1) {
  uint32_t ks2 = k0 ^ k1 ^ 0x1BD11BDAu;
  uint32_t x0 = c0 + k0, x1 = c1 + k1;
  TF_G1(x0, x1); x0 += k1;  x1 += ks2 + 1u;
  TF_G2(x0, x1); x0 += ks2; x1 += k0 + 2u;
  TF_G1(x0, x1); x0 += k0;  x1 += k1 + 3u;
  TF_G2(x0, x1); x0 += k1;  x1 += ks2 + 4u;
  TF_G1(x0, x1); x0 += ks2; x1 += k0 + 5u;
  o0 = x0; o1 = x1;
}

// partitionable-mode draw: counts=(0,cnt), bits = out0 ^ out1
__device__ __forceinline__ uint32_t tf_bits(uint32_t k0, uint32_t k1, uint32_t ks2,
                                            uint32_t cnt) {
  uint32_t x0 = k0;        // c0 = 0
  uint32_t x1 = cnt + k1;
  TF_G1(x0, x1); x0 += k1;  x1 += ks2 + 1u;
  TF_G2(x0, x1); x0 += ks2; x1 += k0 + 2u;
  TF_G1(x0, x1); x0 += k0;  x1 += k1 + 3u;
  TF_G2(x0, x1); x0 += k1;  x1 += ks2 + 4u;
  TF_G1(x0, x1); x0 += ks2; x1 += k0 + 5u;
  return x0 ^ x1;
}

// 32-lane butterfly reduce on a v2f (same order as rounds 1/3: absmax 0.0)
__device__ __forceinline__ v2f bfly(v2f r) {
#pragma unroll
  for (int m = 1; m < 32; m <<= 1) {
    v2f q;
    q.x = __shfl_xor(r.x, m, 32);
    q.y = __shfl_xor(r.y, m, 32);
    r += q;
  }
  return r;
}

// LIF on a pair of outputs (component-wise identical to scalar rounds 1/3)
__device__ __forceinline__ void lif2(v2f I, v2f& V, v2f& A) {
  v2f vv = V + (I - V) * 0.5f;                 // v += (I - v)/tau, tau=2, exact
  float sx = (vv.x >= 1.0f) ? 1.0f : 0.0f;
  float sy = (vv.y >= 1.0f) ? 1.0f : 0.0f;
  A.x += sx; A.y += sy;
  V.x = (1.0f - sx) * vv.x;                    // hard reset (exact: 0 or vv)
  V.y = (1.0f - sy) * vv.y;
}

// xig[row][c] = (floor(x*2^23) << 9) for c<784, else 0 (pad lanes never spike)
__global__ __launch_bounds__(256)
void prep_xi(const float* __restrict__ x, uint32_t* __restrict__ xig) {
  int i = blockIdx.x * 256 + threadIdx.x;
  if (i >= 16384 * 800) return;
  int row = i / 800;
  int c = i - row * 800;
  uint32_t t = 0u;
  if (c < 784) {
    float xv = x[row * 784 + c];
    t = ((uint32_t)(xv * 8388608.0f)) << 9;    // exact: x = k*2^-23, k < 2^23
  }
  xig[i] = t;
}

// 16384 rows, 784 features, 10 outputs, 100 timesteps
// block: 256 threads = 8 rows x 32 lanes; grid 2048; 4 blocks/CU
template <bool USE_XIG>
__global__ __launch_bounds__(256, 4)
void snn_lif_kernel(const float* __restrict__ x, const uint32_t* __restrict__ xig,
                    const float* __restrict__ W, float* __restrict__ out) {
  // Wp[jj][q][jl][4]: q-th float4 of W[:, j=jl+32*jj]  (o = 4q+c; pads = 0)
  __shared__ __align__(16) float Wp[25 * 3 * 32 * 4];
  __shared__ uint32_t keys[100][2];

  const int tid = threadIdx.x;

  for (int s = tid; s < 25 * 3 * 32 * 4; s += 256) {
    int c = s & 3;
    int jl = (s >> 2) & 31;
    int rest = s >> 7;
    int q = rest % 3;
    int jj = rest / 3;
    int o = q * 4 + c;
    int j = jl + 32 * jj;
    float w = 0.0f;
    if (o < 10 && j < 784) w = W[o * 784 + j];
    Wp[s] = w;
  }
  if (tid < 100) {
    threefry_full(0u, 42u, 0u, (uint32_t)tid, keys[tid][0], keys[tid][1]);
  }
  __syncthreads();

  const int row = blockIdx.x * 8 + (tid >> 5);
  const int hl = tid & 31;
  const uint32_t cntbase = (uint32_t)row * 784u + (uint32_t)hl;

  // thresholds: s-base + 32-bit voffset + per-jj immediate offset, zero VALU addr
  const uint32_t* xrow_i = xig + (size_t)row * 800 + hl;
  const float* xrow = x + (size_t)row * 784;

  v2f V0 = {0, 0}, V1 = {0, 0}, V2 = {0, 0}, V3 = {0, 0}, V4 = {0, 0};
  v2f A0 = {0, 0}, A1 = {0, 0}, A2 = {0, 0}, A3 = {0, 0}, A4 = {0, 0};

  const v4f* wq = (const v4f*)&Wp[(size_t)hl * 4];

  for (int t = 0; t < 100; ++t) {
    const uint32_t k0 = __builtin_amdgcn_readfirstlane(keys[t][0]);
    const uint32_t k1 = __builtin_amdgcn_readfirstlane(keys[t][1]);
    const uint32_t ks2 = k0 ^ k1 ^ 0x1BD11BDAu;

    v2f I0 = {0, 0}, I1 = {0, 0}, I2 = {0, 0}, I3 = {0, 0}, I4 = {0, 0};

#pragma unroll 5
    for (int jj = 0; jj < 25; ++jj) {
      const uint32_t bits = tf_bits(k0, k1, ks2, cntbase + (uint32_t)(jj * 32));

      uint32_t thr;
      if (USE_XIG) {
        thr = xrow_i[jj * 32];                        // pads stored as 0
      } else {
        int j = hl + jj * 32;
        float xv = xrow[(j < 784) ? j : 783];
        uint32_t k = (uint32_t)(xv * 8388608.0f);
        thr = (j < 784) ? (k << 9) : 0u;
      }
      const float s = (bits < thr) ? 1.0f : 0.0f;     // bit-exact u < x
      const v2f s2 = {s, s};

      const v4f wa = wq[jj * 96];
      const v4f wb = wq[jj * 96 + 32];
      const v4f wc = wq[jj * 96 + 64];
      I0 += s2 * wa.lo;
      I1 += s2 * wa.hi;
      I2 += s2 * wb.lo;
      I3 += s2 * wb.hi;
      I4 += s2 * wc.lo;
    }

    I0 = bfly(I0); I1 = bfly(I1); I2 = bfly(I2); I3 = bfly(I3); I4 = bfly(I4);

    lif2(I0, V0, A0);
    lif2(I1, V1, A1);
    lif2(I2, V2, A2);
    lif2(I3, V3, A3);
    lif2(I4, V4, A4);
  }

  if (hl == 0) {
    float* orow = out + (size_t)row * 10;
    orow[0] = A0.x / 100.0f; orow[1] = A0.y / 100.0f;
    orow[2] = A1.x / 100.0f; orow[3] = A1.y / 100.0f;
    orow[4] = A2.x / 100.0f; orow[5] = A2.y / 100.0f;
    orow[6] = A3.x / 100.0f; orow[7] = A3.y / 100.0f;
    orow[8] = A4.x / 100.0f; orow[9] = A4.y / 100.0f;
  }
}

extern "C" void kernel_launch(void* const* d_in, const int* in_sizes, int n_in,
                              void* d_out, int out_size, void* d_ws, size_t ws_size,
                              hipStream_t stream) {
  const float* x = (const float*)d_in[0];   // [16384,1,28,28] fp32
  const float* W = (const float*)d_in[1];   // [10,784] fp32
  float* out = (float*)d_out;               // [16384,10] fp32

  const size_t need = (size_t)16384 * 800 * 4;   // 52.4 MB threshold table
  if (ws_size >= need) {
    uint32_t* xig = (uint32_t*)d_ws;
    hipLaunchKernelGGL(prep_xi, dim3((16384 * 800 + 255) / 256), dim3(256), 0,
                       stream, x, xig);
    hipLaunchKernelGGL((snn_lif_kernel<true>), dim3(2048), dim3(256), 0, stream,
                       x, xig, W, out);
  } else {
    hipLaunchKernelGGL((snn_lif_kernel<false>), dim3(2048), dim3(256), 0, stream,
                       x, (const uint32_t*)nullptr, W, out);
  }
}